// Round 1
// baseline (6522.758 us; speedup 1.0000x reference)
//
#include <hip/hip_runtime.h>
#include <hip/hip_bf16.h>
#include <stdint.h>

#define T_STEPS 512
#define BATCH   64
#define HID     1024

typedef short bf16x8 __attribute__((ext_vector_type(8)));
typedef float f32x4  __attribute__((ext_vector_type(4)));

static __device__ __forceinline__ unsigned short bf16_rne(float f) {
    unsigned u = __builtin_bit_cast(unsigned, f);
    unsigned r = u + 0x7fffu + ((u >> 16) & 1u);
    return (unsigned short)(r >> 16);
}
static __device__ __forceinline__ float bf16tof(unsigned short h) {
    unsigned u = ((unsigned)h) << 16;
    return __builtin_bit_cast(float, u);
}

// ---------------- K1: transpose + convert W_xh [K][N] f32 -> Wt [N][K] bf16 ---
__global__ __launch_bounds__(256) void k_transpose(const float* __restrict__ W,
                                                   unsigned short* __restrict__ Wt) {
    __shared__ float tile[64][65];
    int bx = blockIdx.x & 15, by = blockIdx.x >> 4;
    int n0 = bx * 64, k0 = by * 64;
    int tx = threadIdx.x & 63, ty = threadIdx.x >> 6;
#pragma unroll
    for (int p = 0; p < 16; ++p) {
        int r = p * 4 + ty;
        tile[r][tx] = W[(size_t)(k0 + r) * 1024 + n0 + tx];
    }
    __syncthreads();
#pragma unroll
    for (int p = 0; p < 16; ++p) {
        int r = p * 4 + ty;
        Wt[(size_t)(n0 + r) * 1024 + k0 + tx] = bf16_rne(tile[tx][r]);
    }
}

// ---------------- K2: Xp = X @ W_xh + b_h  (bf16 MFMA, 128x128x32 tiles) ------
#define LDA 80  // padded LDS row stride in bytes (64B data + 16B pad, conflict-free)

__global__ __launch_bounds__(256) void k_xpgemm(const float* __restrict__ X,
                                                const unsigned short* __restrict__ Wt,
                                                const float* __restrict__ bh,
                                                unsigned short* __restrict__ Xp) {
    __shared__ __align__(16) unsigned char ldsA[128 * LDA];
    __shared__ __align__(16) unsigned char ldsB[128 * LDA];
    int p = blockIdx.x;
    int lo = (p & 7) * 256 + (p >> 3);  // XCD-aware swizzle (2048 % 8 == 0)
    int mt = lo >> 3, nt = lo & 7;
    int m0 = mt * 128, n0 = nt * 128;
    int tid = threadIdx.x;
    int lane = tid & 63, wid = tid >> 6;
    int wr = wid >> 1, wc = wid & 1;
    int mw = wr * 64, nw = wc * 64;
    int l15 = lane & 15, kg = lane >> 4;

    f32x4 acc[4][4] = {};
    int arow = tid >> 3, as = tid & 7;  // A staging: 32 rows/pass x4, float4 each
    int brow = tid >> 2, bs = tid & 3;  // B staging: 64 rows/pass x2, 16B each

    for (int kt = 0; kt < 32; ++kt) {
        // stage A: [128][32] f32 -> bf16 in LDS (reg-staged, RNE convert)
#pragma unroll
        for (int pp = 0; pp < 4; ++pp) {
            int r = pp * 32 + arow;
            const float4 v = *(const float4*)(X + (size_t)(m0 + r) * 1024 + kt * 32 + as * 4);
            unsigned lo32 = ((unsigned)bf16_rne(v.y) << 16) | bf16_rne(v.x);
            unsigned hi32 = ((unsigned)bf16_rne(v.w) << 16) | bf16_rne(v.z);
            *(uint2*)(ldsA + r * LDA + as * 8) = make_uint2(lo32, hi32);
        }
        // stage B: Wt rows (already bf16, [n][k] layout)
#pragma unroll
        for (int pp = 0; pp < 2; ++pp) {
            int r = pp * 64 + brow;
            uint4 v = *(const uint4*)(Wt + (size_t)(n0 + r) * 1024 + kt * 32 + bs * 8);
            *(uint4*)(ldsB + r * LDA + bs * 16) = v;
        }
        __syncthreads();
        bf16x8 af[4];
#pragma unroll
        for (int i = 0; i < 4; ++i)
            af[i] = *(const bf16x8*)(ldsA + (mw + 16 * i + l15) * LDA + kg * 16);
#pragma unroll
        for (int j = 0; j < 4; ++j) {
            bf16x8 bfj = *(const bf16x8*)(ldsB + (nw + 16 * j + l15) * LDA + kg * 16);
#pragma unroll
            for (int i = 0; i < 4; ++i)
                acc[i][j] = __builtin_amdgcn_mfma_f32_16x16x32_bf16(af[i], bfj, acc[i][j], 0, 0, 0);
        }
        __syncthreads();
    }
    // epilogue: add bias, store bf16 Xp
#pragma unroll
    for (int j = 0; j < 4; ++j) {
        int col = n0 + nw + 16 * j + l15;
        float bias = bh[col];
#pragma unroll
        for (int i = 0; i < 4; ++i) {
            int rb = m0 + mw + 16 * i + kg * 4;
#pragma unroll
            for (int r = 0; r < 4; ++r)
                Xp[(size_t)(rb + r) * 1024 + col] = bf16_rne(acc[i][j][r] + bias);
        }
    }
}

// ---------------- K3: the scan. 256 single-wave WGs; W_hh slice in registers. -
__global__ __launch_bounds__(64, 1) void k_scan(const float* __restrict__ Whh,
                                                const unsigned short* __restrict__ Xp,
                                                unsigned short* __restrict__ hbuf, // [2][64][1024] bf16
                                                unsigned int* flags,               // [256]
                                                float* __restrict__ out) {
    const int wid = blockIdx.x;    // 0..255
    const int lane = threadIdx.x;  // 0..63
    const int ct = wid & 63, rt = wid >> 6;
    const int j0 = ct * 16, b0 = rt * 16;
    const int l15 = lane & 15, kg = lane >> 4;
    const int jj = j0 + l15;
    const int rbase = b0 + kg * 4;

    // preload W_hh column-slice into registers (bf16), resident for all 512 steps
    bf16x8 w[32];
#pragma unroll
    for (int ks = 0; ks < 32; ++ks) {
#pragma unroll
        for (int e = 0; e < 8; ++e) {
            float v = Whh[(size_t)(ks * 32 + kg * 8 + e) * 1024 + jj];
            w[ks][e] = (short)bf16_rne(v);
        }
    }

    const unsigned int* myf = flags + lane * 4;

    for (int t = 0; t < T_STEPS; ++t) {
        // prefetch xp tile (independent of flags -> overlaps poll latency)
        float xpv[4];
#pragma unroll
        for (int r = 0; r < 4; ++r)
            xpv[r] = bf16tof(Xp[(size_t)(t * 64 + rbase + r) * 1024 + jj]);

        if (t > 0) {
            unsigned tt = (unsigned)t;
            for (;;) {
                unsigned f0 = __hip_atomic_load(myf + 0, __ATOMIC_RELAXED, __HIP_MEMORY_SCOPE_AGENT);
                unsigned f1 = __hip_atomic_load(myf + 1, __ATOMIC_RELAXED, __HIP_MEMORY_SCOPE_AGENT);
                unsigned f2 = __hip_atomic_load(myf + 2, __ATOMIC_RELAXED, __HIP_MEMORY_SCOPE_AGENT);
                unsigned f3 = __hip_atomic_load(myf + 3, __ATOMIC_RELAXED, __HIP_MEMORY_SCOPE_AGENT);
                if (f0 >= tt && f1 >= tt && f2 >= tt && f3 >= tt) break;
                __builtin_amdgcn_s_sleep(1);
            }
            __builtin_amdgcn_fence(__ATOMIC_ACQUIRE, "agent");
        }

        const unsigned short* hp =
            hbuf + (size_t)(t & 1) * 65536 + (size_t)(b0 + l15) * 1024 + kg * 8;
        f32x4 a0 = {0.f, 0.f, 0.f, 0.f}, a1 = {0.f, 0.f, 0.f, 0.f};
        f32x4 a2 = {0.f, 0.f, 0.f, 0.f}, a3 = {0.f, 0.f, 0.f, 0.f};
#pragma unroll
        for (int ks = 0; ks < 8; ++ks) {
            bf16x8 v0 = *(const bf16x8*)(hp + (4 * ks + 0) * 32);
            bf16x8 v1 = *(const bf16x8*)(hp + (4 * ks + 1) * 32);
            bf16x8 v2 = *(const bf16x8*)(hp + (4 * ks + 2) * 32);
            bf16x8 v3 = *(const bf16x8*)(hp + (4 * ks + 3) * 32);
            a0 = __builtin_amdgcn_mfma_f32_16x16x32_bf16(v0, w[4 * ks + 0], a0, 0, 0, 0);
            a1 = __builtin_amdgcn_mfma_f32_16x16x32_bf16(v1, w[4 * ks + 1], a1, 0, 0, 0);
            a2 = __builtin_amdgcn_mfma_f32_16x16x32_bf16(v2, w[4 * ks + 2], a2, 0, 0, 0);
            a3 = __builtin_amdgcn_mfma_f32_16x16x32_bf16(v3, w[4 * ks + 3], a3, 0, 0, 0);
        }
        f32x4 acc = (a0 + a1) + (a2 + a3);

        float hv[4];
#pragma unroll
        for (int r = 0; r < 4; ++r) {
            float z = acc[r] + xpv[r];
            z = fminf(fmaxf(z, -15.f), 15.f);
            float e = __expf(2.f * z);
            hv[r] = (e - 1.f) / (e + 1.f);
            out[(size_t)(t * 64 + rbase + r) * 1024 + jj] = hv[r];
        }
        if (t == T_STEPS - 1) {
#pragma unroll
            for (int r = 0; r < 4; ++r)
                out[(size_t)33554432 + (size_t)(rbase + r) * 1024 + jj] = hv[r];
        }
        unsigned short* hn = hbuf + (size_t)((t + 1) & 1) * 65536;
#pragma unroll
        for (int r = 0; r < 4; ++r)
            hn[(rbase + r) * 1024 + jj] = bf16_rne(hv[r]);

        if (t < T_STEPS - 1) {
            __builtin_amdgcn_fence(__ATOMIC_RELEASE, "agent");
            if (lane == 0)
                __hip_atomic_store(&flags[wid], (unsigned)(t + 1), __ATOMIC_RELAXED,
                                   __HIP_MEMORY_SCOPE_AGENT);
        }
    }
}

// ---------------- launcher ---------------------------------------------------
extern "C" void kernel_launch(void* const* d_in, const int* in_sizes, int n_in,
                              void* d_out, int out_size, void* d_ws, size_t ws_size,
                              hipStream_t stream) {
    const float* X   = (const float*)d_in[0];
    const float* Wxh = (const float*)d_in[1];
    const float* Whh = (const float*)d_in[2];
    const float* bh  = (const float*)d_in[3];
    float* out = (float*)d_out;
    unsigned char* ws = (unsigned char*)d_ws;

    // workspace layout (bytes):
    //   [0)            Wt     : 2,097,152   (W_xh^T bf16 [N][K])
    //   [2097152)      Xp     : 67,108,864  (bf16 [T*B][H])
    //   [69206016)     hbuf   : 262,144     (bf16 [2][64][1024])
    //   [69468160)     flags  : 1,024       (u32 [256])
    unsigned short* Wt    = (unsigned short*)(ws + 0);
    unsigned short* Xp    = (unsigned short*)(ws + 2097152);
    unsigned short* hbuf  = (unsigned short*)(ws + 69206016);
    unsigned int*   flags = (unsigned int*)(ws + 69468160);

    hipMemsetAsync(ws + 69206016, 0, 262144 + 1024, stream);  // h(0)=0, flags=0
    hipLaunchKernelGGL(k_transpose, dim3(256), dim3(256), 0, stream, Wxh, Wt);
    hipLaunchKernelGGL(k_xpgemm, dim3(2048), dim3(256), 0, stream, X, Wt, bh, Xp);
    hipLaunchKernelGGL(k_scan, dim3(256), dim3(64), 0, stream, Whh, Xp, hbuf, flags, out);
}

// Round 2
// 2214.199 us; speedup vs baseline: 2.9459x; 2.9459x over previous
//
#include <hip/hip_runtime.h>
#include <hip/hip_bf16.h>
#include <stdint.h>

#define T_STEPS 512
#define BATCH   64
#define HID     1024

typedef short bf16x8 __attribute__((ext_vector_type(8)));
typedef float f32x4  __attribute__((ext_vector_type(4)));
typedef unsigned int u32x4 __attribute__((ext_vector_type(4)));

static __device__ __forceinline__ unsigned short bf16_rne(float f) {
    unsigned u = __builtin_bit_cast(unsigned, f);
    unsigned r = u + 0x7fffu + ((u >> 16) & 1u);
    return (unsigned short)(r >> 16);
}
static __device__ __forceinline__ float bf16tof(unsigned short h) {
    unsigned u = ((unsigned)h) << 16;
    return __builtin_bit_cast(float, u);
}

// ---------------- K1: transpose + convert W_xh [K][N] f32 -> Wt [N][K] bf16 ---
__global__ __launch_bounds__(256) void k_transpose(const float* __restrict__ W,
                                                   unsigned short* __restrict__ Wt) {
    __shared__ float tile[64][65];
    int bx = blockIdx.x & 15, by = blockIdx.x >> 4;
    int n0 = bx * 64, k0 = by * 64;
    int tx = threadIdx.x & 63, ty = threadIdx.x >> 6;
#pragma unroll
    for (int p = 0; p < 16; ++p) {
        int r = p * 4 + ty;
        tile[r][tx] = W[(size_t)(k0 + r) * 1024 + n0 + tx];
    }
    __syncthreads();
#pragma unroll
    for (int p = 0; p < 16; ++p) {
        int r = p * 4 + ty;
        Wt[(size_t)(n0 + r) * 1024 + k0 + tx] = bf16_rne(tile[tx][r]);
    }
}

// ---------------- K2: Xp = X @ W_xh + b_h  (bf16 MFMA, 128x128x32 tiles) ------
#define LDA 80  // padded LDS row stride in bytes (64B data + 16B pad, conflict-free)

__global__ __launch_bounds__(256) void k_xpgemm(const float* __restrict__ X,
                                                const unsigned short* __restrict__ Wt,
                                                const float* __restrict__ bh,
                                                unsigned short* __restrict__ Xp) {
    __shared__ __align__(16) unsigned char ldsA[128 * LDA];
    __shared__ __align__(16) unsigned char ldsB[128 * LDA];
    int p = blockIdx.x;
    int lo = (p & 7) * 256 + (p >> 3);  // XCD-aware swizzle (2048 % 8 == 0)
    int mt = lo >> 3, nt = lo & 7;
    int m0 = mt * 128, n0 = nt * 128;
    int tid = threadIdx.x;
    int lane = tid & 63, wid = tid >> 6;
    int wr = wid >> 1, wc = wid & 1;
    int mw = wr * 64, nw = wc * 64;
    int l15 = lane & 15, kg = lane >> 4;

    f32x4 acc[4][4] = {};
    int arow = tid >> 3, as = tid & 7;
    int brow = tid >> 2, bs = tid & 3;

    for (int kt = 0; kt < 32; ++kt) {
#pragma unroll
        for (int pp = 0; pp < 4; ++pp) {
            int r = pp * 32 + arow;
            const float4 v = *(const float4*)(X + (size_t)(m0 + r) * 1024 + kt * 32 + as * 4);
            unsigned lo32 = ((unsigned)bf16_rne(v.y) << 16) | bf16_rne(v.x);
            unsigned hi32 = ((unsigned)bf16_rne(v.w) << 16) | bf16_rne(v.z);
            *(uint2*)(ldsA + r * LDA + as * 8) = make_uint2(lo32, hi32);
        }
#pragma unroll
        for (int pp = 0; pp < 2; ++pp) {
            int r = pp * 64 + brow;
            uint4 v = *(const uint4*)(Wt + (size_t)(n0 + r) * 1024 + kt * 32 + bs * 8);
            *(uint4*)(ldsB + r * LDA + bs * 16) = v;
        }
        __syncthreads();
        bf16x8 af[4];
#pragma unroll
        for (int i = 0; i < 4; ++i)
            af[i] = *(const bf16x8*)(ldsA + (mw + 16 * i + l15) * LDA + kg * 16);
#pragma unroll
        for (int j = 0; j < 4; ++j) {
            bf16x8 bfj = *(const bf16x8*)(ldsB + (nw + 16 * j + l15) * LDA + kg * 16);
#pragma unroll
            for (int i = 0; i < 4; ++i)
                acc[i][j] = __builtin_amdgcn_mfma_f32_16x16x32_bf16(af[i], bfj, acc[i][j], 0, 0, 0);
        }
        __syncthreads();
    }
#pragma unroll
    for (int j = 0; j < 4; ++j) {
        int col = n0 + nw + 16 * j + l15;
        float bias = bh[col];
#pragma unroll
        for (int i = 0; i < 4; ++i) {
            int rb = m0 + mw + 16 * i + kg * 4;
#pragma unroll
            for (int r = 0; r < 4; ++r)
                Xp[(size_t)(rb + r) * 1024 + col] = bf16_rne(acc[i][j][r] + bias);
        }
    }
}

// ---------------- K3: the scan. 256 single-wave WGs; W_hh slice in registers. -
// Cross-XCD communication via per-access L1/L2-bypass (sc0 sc1) loads/stores to
// the coherent Infinity Cache. NO agent fences (no buffer_wbl2 / buffer_inv).
__global__ __launch_bounds__(64, 1) void k_scan(const float* __restrict__ Whh,
                                                const unsigned short* __restrict__ Xp,
                                                unsigned short* __restrict__ hbuf, // [2][64][1024] bf16
                                                unsigned int* flags,               // [256]
                                                float* __restrict__ out) {
    const int wid = blockIdx.x;    // 0..255
    const int lane = threadIdx.x;  // 0..63
    const int ct = wid & 63, rt = wid >> 6;
    const int j0 = ct * 16, b0 = rt * 16;
    const int l15 = lane & 15, kg = lane >> 4;
    const int jj = j0 + l15;
    const int rbase = b0 + kg * 4;

    // preload W_hh column-slice into registers (bf16), resident for all 512 steps
    bf16x8 w[32];
#pragma unroll
    for (int ks = 0; ks < 32; ++ks) {
#pragma unroll
        for (int e = 0; e < 8; ++e) {
            float v = Whh[(size_t)(ks * 32 + kg * 8 + e) * 1024 + jj];
            w[ks][e] = (short)bf16_rne(v);
        }
    }

    // each lane polls ONE flag: the 64 producers of this WG's row group (same rt)
    const uint64_t fp = (uint64_t)(flags + rt * 64 + lane);
    const uint64_t myflag = (uint64_t)(flags + wid);

    for (int t = 0; t < T_STEPS; ++t) {
        // prefetch xp tile (cached loads; overlap with poll)
        float xpv[4];
#pragma unroll
        for (int r = 0; r < 4; ++r)
            xpv[r] = bf16tof(Xp[(size_t)(t * 64 + rbase + r) * 1024 + jj]);

        if (t > 0) {
            unsigned tt = (unsigned)t;
            for (;;) {
                unsigned f;
                asm volatile("global_load_dword %0, %1, off sc0 sc1\n\t"
                             "s_waitcnt vmcnt(0)"
                             : "=v"(f) : "v"(fp) : "memory");
                if (__all((int)(f >= tt))) break;
            }
        }

        // load h(t) fragments: 32 x 16B, L1/L2-bypass (read coherent L3 copy)
        const uint64_t hp = (uint64_t)(hbuf + (size_t)(t & 1) * 65536 +
                                       (size_t)(b0 + l15) * 1024 + kg * 8);
        u32x4 hr[32];
#pragma unroll
        for (int ks = 0; ks < 32; ++ks)
            asm volatile("global_load_dwordx4 %0, %1, off sc0 sc1"
                         : "=v"(hr[ks]) : "v"(hp + (uint64_t)(ks * 64)) : "memory");
        asm volatile("s_waitcnt vmcnt(0)" ::: "memory");
        __builtin_amdgcn_sched_barrier(0);  // keep MFMAs after the waitcnt

        f32x4 a0 = {0.f, 0.f, 0.f, 0.f}, a1 = {0.f, 0.f, 0.f, 0.f};
        f32x4 a2 = {0.f, 0.f, 0.f, 0.f}, a3 = {0.f, 0.f, 0.f, 0.f};
#pragma unroll
        for (int ks = 0; ks < 8; ++ks) {
            a0 = __builtin_amdgcn_mfma_f32_16x16x32_bf16(
                __builtin_bit_cast(bf16x8, hr[4 * ks + 0]), w[4 * ks + 0], a0, 0, 0, 0);
            a1 = __builtin_amdgcn_mfma_f32_16x16x32_bf16(
                __builtin_bit_cast(bf16x8, hr[4 * ks + 1]), w[4 * ks + 1], a1, 0, 0, 0);
            a2 = __builtin_amdgcn_mfma_f32_16x16x32_bf16(
                __builtin_bit_cast(bf16x8, hr[4 * ks + 2]), w[4 * ks + 2], a2, 0, 0, 0);
            a3 = __builtin_amdgcn_mfma_f32_16x16x32_bf16(
                __builtin_bit_cast(bf16x8, hr[4 * ks + 3]), w[4 * ks + 3], a3, 0, 0, 0);
        }
        f32x4 acc = (a0 + a1) + (a2 + a3);

        float hv[4];
        unsigned hb[4];
#pragma unroll
        for (int r = 0; r < 4; ++r) {
            float z = acc[r] + xpv[r];
            z = fminf(fmaxf(z, -15.f), 15.f);
            float e = __expf(2.f * z);
            hv[r] = (e - 1.f) / (e + 1.f);
            hb[r] = (unsigned)bf16_rne(hv[r]);
        }

        if (t < T_STEPS - 1) {
            // store h(t+1) (L2-bypass) -> wait ack at coherence point -> signal
            const uint64_t hn = (uint64_t)(hbuf + (size_t)((t + 1) & 1) * 65536);
#pragma unroll
            for (int r = 0; r < 4; ++r)
                asm volatile("global_store_short %0, %1, off sc0 sc1"
                             :: "v"(hn + (uint64_t)(((rbase + r) * 1024 + jj) * 2)),
                                "v"(hb[r]) : "memory");
            asm volatile("s_waitcnt vmcnt(0)" ::: "memory");
            if (lane == 0)
                asm volatile("global_store_dword %0, %1, off sc0 sc1"
                             :: "v"(myflag), "v"((unsigned)(t + 1)) : "memory");
        }

        // out stores AFTER the signal: off the critical path (plain cached stores)
#pragma unroll
        for (int r = 0; r < 4; ++r)
            out[(size_t)(t * 64 + rbase + r) * 1024 + jj] = hv[r];
        if (t == T_STEPS - 1) {
#pragma unroll
            for (int r = 0; r < 4; ++r)
                out[(size_t)33554432 + (size_t)(rbase + r) * 1024 + jj] = hv[r];
        }
    }
}

// ---------------- launcher ---------------------------------------------------
extern "C" void kernel_launch(void* const* d_in, const int* in_sizes, int n_in,
                              void* d_out, int out_size, void* d_ws, size_t ws_size,
                              hipStream_t stream) {
    const float* X   = (const float*)d_in[0];
    const float* Wxh = (const float*)d_in[1];
    const float* Whh = (const float*)d_in[2];
    const float* bh  = (const float*)d_in[3];
    float* out = (float*)d_out;
    unsigned char* ws = (unsigned char*)d_ws;

    unsigned short* Wt    = (unsigned short*)(ws + 0);
    unsigned short* Xp    = (unsigned short*)(ws + 2097152);
    unsigned short* hbuf  = (unsigned short*)(ws + 69206016);
    unsigned int*   flags = (unsigned int*)(ws + 69468160);

    hipMemsetAsync(ws + 69206016, 0, 262144 + 1024, stream);  // h(0)=0, flags=0
    hipLaunchKernelGGL(k_transpose, dim3(256), dim3(256), 0, stream, Wxh, Wt);
    hipLaunchKernelGGL(k_xpgemm, dim3(2048), dim3(256), 0, stream, X, Wt, bh, Xp);
    hipLaunchKernelGGL(k_scan, dim3(256), dim3(64), 0, stream, Whh, Xp, hbuf, flags, out);
}